// Round 3
// baseline (1615.151 us; speedup 1.0000x reference)
//
#include <hip/hip_runtime.h>

#define EPSF 1e-6f
#define NXCD 8

__device__ __forceinline__ int xcc_id() {
    int x;
    asm volatile("s_getreg_b32 %0, hwreg(HW_REG_XCC_ID)" : "=s"(x));
    return x & (NXCD - 1);
}

// Zero the accumulator copies (capture-safe, no hipMemsetAsync).
__global__ __launch_bounds__(256) void zero_kernel(float4* __restrict__ acc, int n4)
{
    int stride = gridDim.x * blockDim.x;
    for (int i = blockIdx.x * blockDim.x + threadIdx.x; i < n4; i += stride)
        acc[i] = make_float4(0.f, 0.f, 0.f, 0.f);
}

// Edge kernel, XCD-local path: atomics into this XCD's private copy,
// workgroup scope so the RMW stays in the local L2 (all requesters of
// copy[xcd] are on the same XCD -> same L2 -> atomicity holds).
__global__ __launch_bounds__(256) void edge_kernel_xcd(
    const float* __restrict__ vertices,
    const int2*  __restrict__ edges,
    const float4* __restrict__ messages,   // E * 2 float4 (8 floats per edge)
    float* __restrict__ acc,               // [NXCD][N][4]
    int E, int N)
{
    const int xid = xcc_id();
    float* __restrict__ myacc = acc + (size_t)xid * N * 4;

    int stride = gridDim.x * blockDim.x;
    for (int e = blockIdx.x * blockDim.x + threadIdx.x; e < E; e += stride) {
        int2 ed = edges[e];
        float4 m0 = messages[2 * e];
        float4 m1 = messages[2 * e + 1];
        float wgt = (((m0.x + m0.y) + (m0.z + m0.w)) +
                     ((m1.x + m1.y) + (m1.z + m1.w))) * 0.125f;

        const float* xp = vertices + 3 * (size_t)ed.x;
        const float* yp = vertices + 3 * (size_t)ed.y;
        float x0 = xp[0], x1 = xp[1], x2 = xp[2];
        float y0 = yp[0], y1 = yp[1], y2 = yp[2];

        // Minkowski inner product, w = (-1, 1, 1); K = 1
        float t  = x1 * y1 + x2 * y2 - x0 * y0;
        float v0 = y0 + x0 * t;
        float v1 = y1 + x1 * t;
        float v2 = y2 + x2 * t;
        float mipv = v1 * v1 + v2 * v2 - v0 * v0;
        float vn   = sqrtf(mipv + EPSF);
        float dist = acoshf(-t);
        float scale = dist * wgt / vn;

        float* a = myacc + 4 * (size_t)ed.x;
        __hip_atomic_fetch_add(a + 0, v0 * scale, __ATOMIC_RELAXED, __HIP_MEMORY_SCOPE_WORKGROUP);
        __hip_atomic_fetch_add(a + 1, v1 * scale, __ATOMIC_RELAXED, __HIP_MEMORY_SCOPE_WORKGROUP);
        __hip_atomic_fetch_add(a + 2, v2 * scale, __ATOMIC_RELAXED, __HIP_MEMORY_SCOPE_WORKGROUP);
        __hip_atomic_fetch_add(a + 3, 1.0f,      __ATOMIC_RELAXED, __HIP_MEMORY_SCOPE_WORKGROUP);
    }
}

// Fallback edge kernel: single copy, device-scope atomics (slow but correct).
__global__ __launch_bounds__(256) void edge_kernel_dev(
    const float* __restrict__ vertices,
    const int2*  __restrict__ edges,
    const float4* __restrict__ messages,
    float* __restrict__ acc,
    int E)
{
    int stride = gridDim.x * blockDim.x;
    for (int e = blockIdx.x * blockDim.x + threadIdx.x; e < E; e += stride) {
        int2 ed = edges[e];
        float4 m0 = messages[2 * e];
        float4 m1 = messages[2 * e + 1];
        float wgt = (((m0.x + m0.y) + (m0.z + m0.w)) +
                     ((m1.x + m1.y) + (m1.z + m1.w))) * 0.125f;

        const float* xp = vertices + 3 * (size_t)ed.x;
        const float* yp = vertices + 3 * (size_t)ed.y;
        float x0 = xp[0], x1 = xp[1], x2 = xp[2];
        float y0 = yp[0], y1 = yp[1], y2 = yp[2];

        float t  = x1 * y1 + x2 * y2 - x0 * y0;
        float v0 = y0 + x0 * t;
        float v1 = y1 + x1 * t;
        float v2 = y2 + x2 * t;
        float mipv = v1 * v1 + v2 * v2 - v0 * v0;
        float vn   = sqrtf(mipv + EPSF);
        float dist = acoshf(-t);
        float scale = dist * wgt / vn;

        float* a = acc + 4 * (size_t)ed.x;
        atomicAdd(a + 0, v0 * scale);
        atomicAdd(a + 1, v1 * scale);
        atomicAdd(a + 2, v2 * scale);
        atomicAdd(a + 3, 1.0f);
    }
}

// Vertex kernel: sum copies, normalize aggregate, apply exp-map.
template <int COPIES>
__global__ __launch_bounds__(256) void vertex_kernel(
    const float* __restrict__ vertices,
    const float4* __restrict__ acc,      // [COPIES][N]
    float* __restrict__ out,
    int N)
{
    int i = blockIdx.x * blockDim.x + threadIdx.x;
    if (i >= N) return;
    float s0 = 0.f, s1 = 0.f, s2 = 0.f, sc = 0.f;
#pragma unroll
    for (int c = 0; c < COPIES; ++c) {
        float4 a = acc[(size_t)c * N + i];
        s0 += a.x; s1 += a.y; s2 += a.z; sc += a.w;
    }
    float g0 = 0.f, g1 = 0.f, g2 = 0.f;
    if (sc > 0.f) {
        g0 = s0 / sc;
        g1 = s1 / sc;
        g2 = s2 / sc;
    }
    float an = sqrtf(g1 * g1 + g2 * g2 - g0 * g0 + EPSF);
    float ch = coshf(an);
    float sh = sinhf(an) / an;   // sqrt(K) = 1
    size_t b = 3 * (size_t)i;
    out[b + 0] = ch * vertices[b + 0] + sh * g0;
    out[b + 1] = ch * vertices[b + 1] + sh * g1;
    out[b + 2] = ch * vertices[b + 2] + sh * g2;
}

extern "C" void kernel_launch(void* const* d_in, const int* in_sizes, int n_in,
                              void* d_out, int out_size, void* d_ws, size_t ws_size,
                              hipStream_t stream)
{
    const float*  vertices = (const float*)d_in[0];
    const int2*   edges    = (const int2*)d_in[1];
    const float4* messages = (const float4*)d_in[2];
    float* out = (float*)d_out;

    int N = in_sizes[0] / 3;   // 500000
    int E = in_sizes[1] / 2;   // 8000000

    float* acc = (float*)d_ws;
    const int blk = 256;

    size_t need = (size_t)NXCD * N * 4 * sizeof(float);   // 64 MB
    if (ws_size >= need) {
        int n4 = NXCD * N;   // float4 count
        zero_kernel<<<4096, blk, 0, stream>>>((float4*)acc, n4);
        edge_kernel_xcd<<<4096, blk, 0, stream>>>(vertices, edges, messages, acc, E, N);
        vertex_kernel<NXCD><<<(N + blk - 1) / blk, blk, 0, stream>>>(vertices, (const float4*)acc, out, N);
    } else {
        zero_kernel<<<4096, blk, 0, stream>>>((float4*)acc, N);
        edge_kernel_dev<<<4096, blk, 0, stream>>>(vertices, edges, messages, acc, E);
        vertex_kernel<1><<<(N + blk - 1) / blk, blk, 0, stream>>>(vertices, (const float4*)acc, out, N);
    }
}

// Round 4
// 304.327 us; speedup vs baseline: 5.3073x; 5.3073x over previous
//
#include <hip/hip_runtime.h>

#define EPSF 1e-6f
#define VB 4096          // vertices per bucket (2^VB_SHIFT)
#define VB_SHIFT 12
#define CHUNK 4096       // edges per chunk
#define NBMAX 128
#define NSLICE 2

// ---------------- binned pipeline ----------------

// K1: per-chunk histogram of src buckets
__global__ __launch_bounds__(512) void count_kernel(const int2* __restrict__ edges,
                                                    int* __restrict__ counts,
                                                    int E, int nb)
{
    __shared__ int hist[NBMAX];
    int c = blockIdx.x;
    int base = c * CHUNK;
    int cnt = min(CHUNK, E - base);
    for (int i = threadIdx.x; i < nb; i += 512) hist[i] = 0;
    __syncthreads();
    for (int k = threadIdx.x; k < cnt; k += 512) {
        int src = edges[base + k].x;
        atomicAdd(&hist[src >> VB_SHIFT], 1);
    }
    __syncthreads();
    for (int i = threadIdx.x; i < nb; i += 512) counts[(size_t)c * nb + i] = hist[i];
}

// K2a: per-bucket exclusive scan over chunks (in-place counts -> rel), one wave per bucket
__global__ __launch_bounds__(64) void relscan_kernel(int* __restrict__ counts,
                                                     int* __restrict__ totals,
                                                     int nb, int nchunk)
{
    int b = blockIdx.x;
    int lane = threadIdx.x;
    int running = 0;
    for (int cbase = 0; cbase < nchunk; cbase += 64) {
        int c = cbase + lane;
        int v = (c < nchunk) ? counts[(size_t)c * nb + b] : 0;
        int s = v;
        for (int d = 1; d < 64; d <<= 1) {
            int o = __shfl_up(s, d);
            if (lane >= d) s += o;
        }
        if (c < nchunk) counts[(size_t)c * nb + b] = running + (s - v);
        running += __shfl(s, 63);
    }
    if (lane == 0) totals[b] = running;
}

// K2b: serial scan over bucket totals -> bucketStart[nb+1]
__global__ __launch_bounds__(64) void bstart_kernel(const int* __restrict__ totals,
                                                    int* __restrict__ bucketStart, int nb)
{
    if (threadIdx.x == 0 && blockIdx.x == 0) {
        int run = 0;
        for (int b = 0; b < nb; ++b) { bucketStart[b] = run; run += totals[b]; }
        bucketStart[nb] = run;
    }
}

// K3: compute weights, counting-sort each chunk in LDS, write bucket-contiguous runs
__global__ __launch_bounds__(512) void scatter_kernel(const int2* __restrict__ edges,
    const float4* __restrict__ messages,
    const int* __restrict__ rel,          // [nchunk][nb] exclusive-within-bucket
    const int* __restrict__ bucketStart,  // [nb+1]
    unsigned int* __restrict__ bsd,
    float* __restrict__ bw,
    int E, int nb)
{
    __shared__ unsigned int  s_pack[CHUNK];
    __shared__ float         s_w[CHUNK];
    __shared__ unsigned char s_b[CHUNK];
    __shared__ int hist[NBMAX], lstart[NBMAX], cursor[NBMAX], goff[NBMAX];

    int c = blockIdx.x;
    int base = c * CHUNK;
    int cnt = min(CHUNK, E - base);

    for (int i = threadIdx.x; i < nb; i += 512) hist[i] = 0;
    __syncthreads();

    int2 ed[8]; float wg[8];
#pragma unroll
    for (int j = 0; j < 8; ++j) {
        int k = threadIdx.x + j * 512;
        if (k < cnt) {
            int2 e2 = edges[base + k];
            float4 m0 = messages[2 * (size_t)(base + k)];
            float4 m1 = messages[2 * (size_t)(base + k) + 1];
            ed[j] = e2;
            wg[j] = (((m0.x + m0.y) + (m0.z + m0.w)) +
                     ((m1.x + m1.y) + (m1.z + m1.w))) * 0.125f;
            atomicAdd(&hist[e2.x >> VB_SHIFT], 1);
        }
    }
    __syncthreads();
    if (threadIdx.x == 0) {
        int run = 0;
        for (int b = 0; b < nb; ++b) { lstart[b] = run; cursor[b] = run; run += hist[b]; }
    }
    __syncthreads();
#pragma unroll
    for (int j = 0; j < 8; ++j) {
        int k = threadIdx.x + j * 512;
        if (k < cnt) {
            int b = ed[j].x >> VB_SHIFT;
            int pos = atomicAdd(&cursor[b], 1);
            s_pack[pos] = ((unsigned int)(ed[j].x & (VB - 1)) << 19) | (unsigned int)ed[j].y;
            s_w[pos]    = wg[j];
            s_b[pos]    = (unsigned char)b;
        }
    }
    for (int i = threadIdx.x; i < nb; i += 512)
        goff[i] = bucketStart[i] + rel[(size_t)c * nb + i];
    __syncthreads();
    for (int k = threadIdx.x; k < cnt; k += 512) {
        int b = s_b[k];
        int g = goff[b] + (k - lstart[b]);
        bsd[g] = s_pack[k];
        bw[g]  = s_w[k];
    }
}

// K4: per (bucket, slice): LDS accumulation, plain coalesced flush to partial[slice]
__global__ __launch_bounds__(1024) void accum_kernel(const float* __restrict__ vertices,
    const unsigned int* __restrict__ bsd, const float* __restrict__ bw,
    const int* __restrict__ bucketStart,
    float* __restrict__ partial,   // [NSLICE][4][N]
    int N, int nb)
{
    __shared__ float acc[4][VB];   // 64 KB, SoA -> bank-conflict-free
    int b = blockIdx.x / NSLICE;
    int s = blockIdx.x - b * NSLICE;
    for (int i = threadIdx.x; i < VB; i += 1024) {
        acc[0][i] = 0.f; acc[1][i] = 0.f; acc[2][i] = 0.f; acc[3][i] = 0.f;
    }
    __syncthreads();
    int e0 = bucketStart[b], e1 = bucketStart[b + 1];
    int len = e1 - e0;
    int g0 = e0 + (int)((long long)len * s / NSLICE);
    int g1 = e0 + (int)((long long)len * (s + 1) / NSLICE);
    int vbase = b << VB_SHIFT;
    for (int g = g0 + threadIdx.x; g < g1; g += 1024) {
        unsigned int pack = bsd[g];
        float w = bw[g];
        int dst = (int)(pack & 0x7FFFFu);
        int sl  = (int)(pack >> 19);
        const float* xp = vertices + 3 * (size_t)(vbase + sl);
        const float* yp = vertices + 3 * (size_t)dst;
        float x0 = xp[0], x1 = xp[1], x2 = xp[2];
        float y0 = yp[0], y1 = yp[1], y2 = yp[2];
        float t  = x1 * y1 + x2 * y2 - x0 * y0;      // mip(x,y), w=(-1,1,1)
        float v0 = y0 + x0 * t;
        float v1 = y1 + x1 * t;
        float v2 = y2 + x2 * t;
        float vn = sqrtf(v1 * v1 + v2 * v2 - v0 * v0 + EPSF);
        float scale = acoshf(-t) * w / vn;
        atomicAdd(&acc[0][sl], v0 * scale);
        atomicAdd(&acc[1][sl], v1 * scale);
        atomicAdd(&acc[2][sl], v2 * scale);
        atomicAdd(&acc[3][sl], 1.0f);
    }
    __syncthreads();
    float* pb = partial + (size_t)s * 4 * N;
    for (int i = threadIdx.x; i < VB; i += 1024) {
        int v = vbase + i;
        if (v < N) {
            pb[v]                 = acc[0][i];
            pb[(size_t)N + v]     = acc[1][i];
            pb[2 * (size_t)N + v] = acc[2][i];
            pb[3 * (size_t)N + v] = acc[3][i];
        }
    }
}

// K5: sum partials, normalize, exp-map
__global__ __launch_bounds__(256) void final_kernel(const float* __restrict__ vertices,
    const float* __restrict__ partial, float* __restrict__ out, int N)
{
    int i = blockIdx.x * 256 + threadIdx.x;
    if (i >= N) return;
    float s0 = 0.f, s1 = 0.f, s2 = 0.f, sc = 0.f;
#pragma unroll
    for (int s = 0; s < NSLICE; ++s) {
        const float* pb = partial + (size_t)s * 4 * N;
        s0 += pb[i];
        s1 += pb[(size_t)N + i];
        s2 += pb[2 * (size_t)N + i];
        sc += pb[3 * (size_t)N + i];
    }
    float g0 = 0.f, g1 = 0.f, g2 = 0.f;
    if (sc > 0.f) { g0 = s0 / sc; g1 = s1 / sc; g2 = s2 / sc; }
    float an = sqrtf(g1 * g1 + g2 * g2 - g0 * g0 + EPSF);
    float ch = coshf(an);
    float sh = sinhf(an) / an;   // sqrt(K) = 1
    size_t bix = 3 * (size_t)i;
    out[bix + 0] = ch * vertices[bix + 0] + sh * g0;
    out[bix + 1] = ch * vertices[bix + 1] + sh * g1;
    out[bix + 2] = ch * vertices[bix + 2] + sh * g2;
}

// ---------------- fallback path (known-correct, slow) ----------------

__global__ __launch_bounds__(256) void zero_kernel(float4* __restrict__ acc, int n4)
{
    int stride = gridDim.x * blockDim.x;
    for (int i = blockIdx.x * blockDim.x + threadIdx.x; i < n4; i += stride)
        acc[i] = make_float4(0.f, 0.f, 0.f, 0.f);
}

__global__ __launch_bounds__(256) void edge_kernel_dev(const float* __restrict__ vertices,
    const int2* __restrict__ edges, const float4* __restrict__ messages,
    float* __restrict__ acc, int E)
{
    int stride = gridDim.x * blockDim.x;
    for (int e = blockIdx.x * blockDim.x + threadIdx.x; e < E; e += stride) {
        int2 ed = edges[e];
        float4 m0 = messages[2 * e];
        float4 m1 = messages[2 * e + 1];
        float wgt = (((m0.x + m0.y) + (m0.z + m0.w)) +
                     ((m1.x + m1.y) + (m1.z + m1.w))) * 0.125f;
        const float* xp = vertices + 3 * (size_t)ed.x;
        const float* yp = vertices + 3 * (size_t)ed.y;
        float x0 = xp[0], x1 = xp[1], x2 = xp[2];
        float y0 = yp[0], y1 = yp[1], y2 = yp[2];
        float t  = x1 * y1 + x2 * y2 - x0 * y0;
        float v0 = y0 + x0 * t;
        float v1 = y1 + x1 * t;
        float v2 = y2 + x2 * t;
        float vn = sqrtf(v1 * v1 + v2 * v2 - v0 * v0 + EPSF);
        float scale = acoshf(-t) * wgt / vn;
        float* a = acc + 4 * (size_t)ed.x;
        atomicAdd(a + 0, v0 * scale);
        atomicAdd(a + 1, v1 * scale);
        atomicAdd(a + 2, v2 * scale);
        atomicAdd(a + 3, 1.0f);
    }
}

__global__ __launch_bounds__(256) void vertex_kernel_fb(const float* __restrict__ vertices,
    const float4* __restrict__ acc, float* __restrict__ out, int N)
{
    int i = blockIdx.x * blockDim.x + threadIdx.x;
    if (i >= N) return;
    float4 a = acc[i];
    float g0 = 0.f, g1 = 0.f, g2 = 0.f;
    if (a.w > 0.f) { g0 = a.x / a.w; g1 = a.y / a.w; g2 = a.z / a.w; }
    float an = sqrtf(g1 * g1 + g2 * g2 - g0 * g0 + EPSF);
    float ch = coshf(an);
    float sh = sinhf(an) / an;
    size_t bix = 3 * (size_t)i;
    out[bix + 0] = ch * vertices[bix + 0] + sh * g0;
    out[bix + 1] = ch * vertices[bix + 1] + sh * g1;
    out[bix + 2] = ch * vertices[bix + 2] + sh * g2;
}

// ---------------- launch ----------------

extern "C" void kernel_launch(void* const* d_in, const int* in_sizes, int n_in,
                              void* d_out, int out_size, void* d_ws, size_t ws_size,
                              hipStream_t stream)
{
    const float*  vertices = (const float*)d_in[0];
    const int2*   edges    = (const int2*)d_in[1];
    const float4* messages = (const float4*)d_in[2];
    float* out = (float*)d_out;

    int N = in_sizes[0] / 3;   // 500000
    int E = in_sizes[1] / 2;   // 8000000
    int nb = (N + VB - 1) / VB;
    int nchunk = (E + CHUNK - 1) / CHUNK;

    // workspace layout
    size_t off = 0;
    auto alloc = [&](size_t bytes) { size_t o = off; off = (off + bytes + 255) & ~255ull; return o; };
    size_t o_bsd = alloc((size_t)E * 4);
    size_t o_bw  = alloc((size_t)E * 4);
    size_t o_cnt = alloc((size_t)nchunk * nb * 4);
    size_t o_tot = alloc((size_t)nb * 4);
    size_t o_bst = alloc((size_t)(nb + 1) * 4);
    size_t o_par = alloc((size_t)NSLICE * 4 * (size_t)N * 4);
    size_t need = off;

    if (nb <= NBMAX && (unsigned)N <= (1u << 19) && ws_size >= need) {
        char* w = (char*)d_ws;
        unsigned int* bsd = (unsigned int*)(w + o_bsd);
        float* bw         = (float*)(w + o_bw);
        int* counts       = (int*)(w + o_cnt);
        int* totals       = (int*)(w + o_tot);
        int* bstart       = (int*)(w + o_bst);
        float* partial    = (float*)(w + o_par);

        count_kernel<<<nchunk, 512, 0, stream>>>(edges, counts, E, nb);
        relscan_kernel<<<nb, 64, 0, stream>>>(counts, totals, nb, nchunk);
        bstart_kernel<<<1, 64, 0, stream>>>(totals, bstart, nb);
        scatter_kernel<<<nchunk, 512, 0, stream>>>(edges, messages, counts, bstart,
                                                   bsd, bw, E, nb);
        accum_kernel<<<nb * NSLICE, 1024, 0, stream>>>(vertices, bsd, bw, bstart,
                                                       partial, N, nb);
        final_kernel<<<(N + 255) / 256, 256, 0, stream>>>(vertices, partial, out, N);
    } else {
        // fallback: single-copy device atomics
        float* acc = (float*)d_ws;
        zero_kernel<<<4096, 256, 0, stream>>>((float4*)acc, N);
        edge_kernel_dev<<<4096, 256, 0, stream>>>(vertices, edges, messages, acc, E);
        vertex_kernel_fb<<<(N + 255) / 256, 256, 0, stream>>>(vertices, (const float4*)acc, out, N);
    }
}